// Round 11
// baseline (6320.271 us; speedup 1.0000x reference)
//
#include <hip/hip_runtime.h>
#include <cstddef>
#include <cstdint>

constexpr int kDIM = 768;
constexpr int kM   = 48;
constexpr int kK   = 256;
constexpr int kB   = 2048;
constexpr int kMID = 9216;
constexpr int kH   = 6144;
constexpr int kMK  = 12288;

using bf8v  = __attribute__((ext_vector_type(8))) short;
using f32x4 = __attribute__((ext_vector_type(4))) float;
using s8v   = __attribute__((ext_vector_type(8))) short;

#define GLL16(SRC, DST) __builtin_amdgcn_global_load_lds( \
    (const __attribute__((address_space(1))) void*)(SRC), \
    (__attribute__((address_space(3))) void*)(DST), 16, 0, 0)

// ===========================================================================
// bf16 split helper: x = x1 + x2 + x3 exactly.
// ===========================================================================
__device__ __forceinline__ unsigned short bf16rn(float f) {
  const unsigned u = __float_as_uint(f);
  return (unsigned short)((u + 0x7FFFu + ((u >> 16) & 1u)) >> 16);
}

// ===========================================================================
// f64-accumulating vector GEMM (proven). rot1 fast path + full fallback path.
// ===========================================================================
template<bool HASBIAS, int EPI, typename OUT_T>
__global__ __launch_bounds__(256)
void gemm_nt_acc64(const float* __restrict__ A, const float* __restrict__ W,
                   const float* __restrict__ bias, OUT_T* C,
                   const float* zslog, const float* __restrict__ znoise,
                   int N, int Kd)
{
  __shared__ float As[16][132];
  __shared__ float Bs[16][132];
  const int tid  = (int)threadIdx.x;
  const int row0 = (int)blockIdx.y * 128;
  const int col0 = (int)blockIdx.x * 128;
  const int ty = tid >> 4, tx = tid & 15;
  const int i0 = ty * 8, j0 = tx * 8;
  const int fi1 = tid >> 2;
  const int fi2 = fi1 + 64;
  const int kc  = (tid & 3) * 4;

  const float* Ap1 = A + (size_t)(row0 + fi1) * Kd + kc;
  const float* Ap2 = A + (size_t)(row0 + fi2) * Kd + kc;
  const float* Wp1 = W + (size_t)(col0 + fi1) * Kd + kc;
  const float* Wp2 = W + (size_t)(col0 + fi2) * Kd + kc;

  double acc[8][8];
#pragma unroll
  for (int r = 0; r < 8; ++r)
#pragma unroll
    for (int c = 0; c < 8; ++c) acc[r][c] = 0.0;

  for (int kt = 0; kt < Kd; kt += 16) {
    const float4 a1 = *(const float4*)(Ap1 + kt);
    const float4 a2 = *(const float4*)(Ap2 + kt);
    const float4 b1 = *(const float4*)(Wp1 + kt);
    const float4 b2 = *(const float4*)(Wp2 + kt);
    As[kc + 0][fi1] = a1.x; As[kc + 1][fi1] = a1.y; As[kc + 2][fi1] = a1.z; As[kc + 3][fi1] = a1.w;
    As[kc + 0][fi2] = a2.x; As[kc + 1][fi2] = a2.y; As[kc + 2][fi2] = a2.z; As[kc + 3][fi2] = a2.w;
    Bs[kc + 0][fi1] = b1.x; Bs[kc + 1][fi1] = b1.y; Bs[kc + 2][fi1] = b1.z; Bs[kc + 3][fi1] = b1.w;
    Bs[kc + 0][fi2] = b2.x; Bs[kc + 1][fi2] = b2.y; Bs[kc + 2][fi2] = b2.z; Bs[kc + 3][fi2] = b2.w;
    __syncthreads();
#pragma unroll
    for (int kk = 0; kk < 16; ++kk) {
      const float4 av0 = *(const float4*)&As[kk][i0];
      const float4 av1 = *(const float4*)&As[kk][i0 + 4];
      const float4 bv0 = *(const float4*)&Bs[kk][j0];
      const float4 bv1 = *(const float4*)&Bs[kk][j0 + 4];
      const float ar[8] = {av0.x, av0.y, av0.z, av0.w, av1.x, av1.y, av1.z, av1.w};
      const float br[8] = {bv0.x, bv0.y, bv0.z, bv0.w, bv1.x, bv1.y, bv1.z, bv1.w};
      double bd[8];
#pragma unroll
      for (int c = 0; c < 8; ++c) bd[c] = (double)br[c];
#pragma unroll
      for (int r = 0; r < 8; ++r) {
        const double ad = (double)ar[r];
#pragma unroll
        for (int c = 0; c < 8; ++c)
          acc[r][c] = fma(ad, bd[c], acc[r][c]);
      }
    }
    __syncthreads();
  }

  double bvv[8];
#pragma unroll
  for (int c = 0; c < 8; ++c) bvv[c] = 0.0;
  if (HASBIAS) {
#pragma unroll
    for (int c = 0; c < 8; ++c) bvv[c] = (double)bias[col0 + j0 + c];
  }

#pragma unroll
  for (int r = 0; r < 8; ++r) {
    const size_t gbase = (size_t)(row0 + i0 + r) * N + col0 + j0;
    double o[8];
#pragma unroll
    for (int c = 0; c < 8; ++c) {
      double v = acc[r][c];
      if (HASBIAS) v += bvv[c];
      if (EPI == 1) v = fmax(v, 0.0);
      if (EPI == 2) {
        const double sg = exp((double)zslog[gbase + c]);
        v = tanh(v + sg * (double)znoise[gbase + c]);
      }
      o[c] = v;
    }
    if constexpr (sizeof(OUT_T) == 4) {
      float* dst = (float*)C + gbase;
      ((float4*)dst)[0] = make_float4((float)o[0], (float)o[1], (float)o[2], (float)o[3]);
      ((float4*)dst)[1] = make_float4((float)o[4], (float)o[5], (float)o[6], (float)o[7]);
    } else {
      double* dst = (double*)C + gbase;
#pragma unroll
      for (int c = 0; c < 8; ++c) dst[c] = o[c];
    }
  }
}

// ===========================================================================
// Standalone split (W inputs + fallback helpers)
// ===========================================================================
__global__ __launch_bounds__(256)
void split3_k(const float* __restrict__ in, short* __restrict__ out, size_t n)
{
  const size_t i = ((size_t)blockIdx.x * 256 + threadIdx.x) * 8;
  const float4 v0 = *(const float4*)(in + i);
  const float4 v1 = *(const float4*)(in + i + 4);
  const float f[8] = {v0.x, v0.y, v0.z, v0.w, v1.x, v1.y, v1.z, v1.w};
  s8v o1, o2, o3;
#pragma unroll
  for (int j = 0; j < 8; ++j) {
    const unsigned short b1 = bf16rn(f[j]);
    const float r1 = f[j] - __uint_as_float((unsigned)b1 << 16);
    const unsigned short b2 = bf16rn(r1);
    const float r2 = r1 - __uint_as_float((unsigned)b2 << 16);
    const unsigned short b3 = bf16rn(r2);
    o1[j] = (short)b1; o2[j] = (short)b2; o3[j] = (short)b3;
  }
  *(s8v*)(out + i)         = o1;
  *(s8v*)(out + n + i)     = o2;
  *(s8v*)(out + 2 * n + i) = o3;
}

// ===========================================================================
// bf16x3 MFMA GEMM — round-10 PROVEN core (6.00ms path: 48KB LDS, 3 blk/CU,
// conflict-free swizzle, by-minor + XCD grid). ONLY the epilogue generalizes:
//   EPI 0: C f32            EPI 1: relu -> C f32
//   EPI 2: relu -> 3 bf16 planes (l1 -> h1P)
//   EPI 3: tanh(v + exp(slog)*noise) in f64 -> 3 bf16 planes (mu -> hP;
//          bit-identical to the old mu-f32-store + zh_k pass)
//   EPI 4: plain -> 3 bf16 planes (rot2 -> hrotP)
// Plane writes split the SAME in-register f32 the old split3 pass would have
// read back — numerics bit-identical, ~550MB of HBM round-trips removed.
// ===========================================================================
template<bool HASBIAS, int EPI>
__global__ __launch_bounds__(256, 3)
void gemm3_bf16(const short* __restrict__ A3, const short* __restrict__ W3,
                const float* __restrict__ bias, void* C,
                const float* __restrict__ zslog, const float* __restrict__ znoise,
                int N, int Kd, size_t planeC)
{
  __shared__ short lds[6][4096];   // 48 KiB: tiles 0..2 = A planes, 3..5 = W planes
  short* smem = &lds[0][0];
  const char* smemc = (const char*)smem;

  int wg = (int)blockIdx.x;
  const int nwg = (int)gridDim.x;
  if ((nwg & 7) == 0) { const int q = nwg >> 3; wg = (wg & 7) * q + (wg >> 3); }
  const int nby = kB / 128;                  // 16
  const int by = wg % nby, bx = wg / nby;
  const int row0 = by * 128, col0 = bx * 128;

  const int tid = (int)threadIdx.x;
  const int l = tid & 63, w = tid >> 6;
  const int wr = (w & 1) * 64, wc = (w >> 1) * 64;

  const size_t planeAB = (size_t)2048 * Kd * 2;   // bytes per A plane
  const size_t planeWB = (size_t)N * Kd * 2;      // bytes per W plane
  const char* A3b = (const char*)A3;
  const char* W3b = (const char*)W3;

  const int su = 2 * w;
  const int r0 = su * 16 + (l >> 2), r1 = r0 + 16;
  const int qsw = (((l & 3) ^ ((l >> 3) & 3)) << 4);
  const size_t offA0 = (size_t)(row0 + r0) * Kd * 2 + qsw;
  const size_t offA1 = (size_t)(row0 + r1) * Kd * 2 + qsw;
  const size_t offW0 = (size_t)(col0 + r0) * Kd * 2 + qsw;
  const size_t offW1 = (size_t)(col0 + r1) * Kd * 2 + qsw;
  short* dA0 = smem + (su + 0) * 512;
  short* dA1 = smem + (su + 1) * 512;

  int aoff[3][4], boff[3][4];
#pragma unroll
  for (int p = 0; p < 3; ++p) {
#pragma unroll
    for (int t = 0; t < 4; ++t) {
      const int Ra = wr + t * 16 + (l & 15);
      aoff[p][t] = p * 8192 + Ra * 64 + ((((l >> 4)) ^ ((Ra >> 1) & 3)) << 4);
      const int Rb = wc + t * 16 + (l & 15);
      boff[p][t] = (3 + p) * 8192 + Rb * 64 + ((((l >> 4)) ^ ((Rb >> 1) & 3)) << 4);
    }
  }

  f32x4 acc[4][4];
#pragma unroll
  for (int i = 0; i < 4; ++i)
#pragma unroll
    for (int j = 0; j < 4; ++j) acc[i][j] = f32x4{0.f, 0.f, 0.f, 0.f};

  for (int kt = 0; kt < Kd; kt += 32) {
    const size_t kb = (size_t)kt * 2;
#pragma unroll
    for (int t = 0; t < 3; ++t) {
      GLL16(A3b + t * planeAB + offA0 + kb, dA0 + t * 4096);
      GLL16(A3b + t * planeAB + offA1 + kb, dA1 + t * 4096);
    }
#pragma unroll
    for (int t = 0; t < 3; ++t) {
      GLL16(W3b + t * planeWB + offW0 + kb, dA0 + (3 + t) * 4096);
      GLL16(W3b + t * planeWB + offW1 + kb, dA1 + (3 + t) * 4096);
    }
    __syncthreads();

    bf8v af[3][4], bf_[3][4];
#pragma unroll
    for (int p = 0; p < 3; ++p)
#pragma unroll
      for (int t = 0; t < 4; ++t) {
        af[p][t]  = *(const bf8v*)(smemc + aoff[p][t]);
        bf_[p][t] = *(const bf8v*)(smemc + boff[p][t]);
      }
#pragma unroll
    for (int tr = 0; tr < 4; ++tr)
#pragma unroll
      for (int tc = 0; tc < 4; ++tc) {
        f32x4 c = acc[tr][tc];
        c = __builtin_amdgcn_mfma_f32_16x16x32_bf16(af[0][tr], bf_[0][tc], c, 0, 0, 0);
        c = __builtin_amdgcn_mfma_f32_16x16x32_bf16(af[0][tr], bf_[1][tc], c, 0, 0, 0);
        c = __builtin_amdgcn_mfma_f32_16x16x32_bf16(af[1][tr], bf_[0][tc], c, 0, 0, 0);
        c = __builtin_amdgcn_mfma_f32_16x16x32_bf16(af[0][tr], bf_[2][tc], c, 0, 0, 0);
        c = __builtin_amdgcn_mfma_f32_16x16x32_bf16(af[2][tr], bf_[0][tc], c, 0, 0, 0);
        c = __builtin_amdgcn_mfma_f32_16x16x32_bf16(af[1][tr], bf_[1][tc], c, 0, 0, 0);
        acc[tr][tc] = c;
      }
    __syncthreads();
  }

  // epilogue: C/D layout col=lane&15, row=(lane>>4)*4+reg (HW-verified)
#pragma unroll
  for (int tc = 0; tc < 4; ++tc) {
    const int colg = col0 + wc + tc * 16 + (l & 15);
    float bv = 0.f;
    if (HASBIAS) bv = bias[colg];
#pragma unroll
    for (int tr = 0; tr < 4; ++tr) {
      const int rowg0 = row0 + wr + tr * 16 + ((l >> 4) << 2);
#pragma unroll
      for (int g = 0; g < 4; ++g) {
        const size_t idx = (size_t)(rowg0 + g) * N + colg;
        float v = acc[tr][tc][g];
        if (HASBIAS) v += bv;
        if (EPI == 1 || EPI == 2) v = fmaxf(v, 0.f);
        if (EPI == 3) {
          const double z = (double)v +
                           exp((double)zslog[idx]) * (double)znoise[idx];
          v = (float)tanh(z);
        }
        if (EPI <= 1) {
          ((float*)C)[idx] = v;
        } else {
          short* P = (short*)C;
          const unsigned short b1 = bf16rn(v);
          const float q1 = v - __uint_as_float((unsigned)b1 << 16);
          const unsigned short b2 = bf16rn(q1);
          const float q2 = q1 - __uint_as_float((unsigned)b2 << 16);
          const unsigned short b3 = bf16rn(q2);
          P[idx]              = (short)b1;
          P[planeC + idx]     = (short)b2;
          P[2 * planeC + idx] = (short)b3;
        }
      }
    }
  }
}

// ===========================================================================
// LayerNorm (f64 stats). _sp variant writes 3 bf16 planes (fast path);
// _f32 variant kept for the fallback path.
// ===========================================================================
__global__ __launch_bounds__(256)
void layernorm_sp_k(const double* __restrict__ in, const float* __restrict__ g,
                    const float* __restrict__ b, short* __restrict__ outP, size_t nP)
{
  const int row = (int)blockIdx.x;
  const int tid = (int)threadIdx.x;
  const double* x = in + (size_t)row * kDIM;
  const double v0 = x[tid], v1 = x[tid + 256], v2 = x[tid + 512];
  __shared__ double red[8];
  double s = v0 + v1 + v2;
#pragma unroll
  for (int off = 32; off; off >>= 1) s += __shfl_xor(s, off);
  if ((tid & 63) == 0) red[tid >> 6] = s;
  __syncthreads();
  const double mean = (red[0] + red[1] + red[2] + red[3]) * (1.0 / 768.0);
  const double d0 = v0 - mean, d1 = v1 - mean, d2 = v2 - mean;
  double q = d0 * d0 + d1 * d1 + d2 * d2;
#pragma unroll
  for (int off = 32; off; off >>= 1) q += __shfl_xor(q, off);
  if ((tid & 63) == 0) red[4 + (tid >> 6)] = q;
  __syncthreads();
  const double var = (red[4] + red[5] + red[6] + red[7]) * (1.0 / 768.0);
  const double rs = 1.0 / sqrt(var + 1e-5);
  const double dd[3] = {d0, d1, d2};
#pragma unroll
  for (int j = 0; j < 3; ++j) {
    const int c = tid + j * 256;
    const float y = (float)(dd[j] * rs * (double)g[c] + (double)b[c]);
    const size_t idx = (size_t)row * kDIM + c;
    const unsigned short b1 = bf16rn(y);
    const float r1 = y - __uint_as_float((unsigned)b1 << 16);
    const unsigned short b2 = bf16rn(r1);
    const float r2 = r1 - __uint_as_float((unsigned)b2 << 16);
    const unsigned short b3 = bf16rn(r2);
    outP[idx] = (short)b1; outP[nP + idx] = (short)b2; outP[2 * nP + idx] = (short)b3;
  }
}

__global__ __launch_bounds__(256)
void layernorm_f32_k(const double* __restrict__ in, const float* __restrict__ g,
                     const float* __restrict__ b, float* __restrict__ out)
{
  const int row = (int)blockIdx.x;
  const int tid = (int)threadIdx.x;
  const double* x = in + (size_t)row * kDIM;
  const double v0 = x[tid], v1 = x[tid + 256], v2 = x[tid + 512];
  __shared__ double red[8];
  double s = v0 + v1 + v2;
#pragma unroll
  for (int off = 32; off; off >>= 1) s += __shfl_xor(s, off);
  if ((tid & 63) == 0) red[tid >> 6] = s;
  __syncthreads();
  const double mean = (red[0] + red[1] + red[2] + red[3]) * (1.0 / 768.0);
  const double d0 = v0 - mean, d1 = v1 - mean, d2 = v2 - mean;
  double q = d0 * d0 + d1 * d1 + d2 * d2;
#pragma unroll
  for (int off = 32; off; off >>= 1) q += __shfl_xor(q, off);
  if ((tid & 63) == 0) red[4 + (tid >> 6)] = q;
  __syncthreads();
  const double var = (red[4] + red[5] + red[6] + red[7]) * (1.0 / 768.0);
  const double rs = 1.0 / sqrt(var + 1e-5);
  float* y = out + (size_t)row * kDIM;
  y[tid]       = (float)(d0 * rs * (double)g[tid]       + (double)b[tid]);
  y[tid + 256] = (float)(d1 * rs * (double)g[tid + 256] + (double)b[tid + 256]);
  y[tid + 512] = (float)(d2 * rs * (double)g[tid + 512] + (double)b[tid + 512]);
}

// ===========================================================================
// PQ argmin + finalize (f64 decision paths, proven)
// ===========================================================================
__global__ __launch_bounds__(256)
void mindist_k(const double* __restrict__ xrot, const float* __restrict__ cb,
               int* __restrict__ minidx)
{
  const int wid  = (int)blockIdx.x * 4 + ((int)threadIdx.x >> 6);
  const int lane = (int)threadIdx.x & 63;
  const int bi = wid / kM, mi = wid % kM;
  const double* xv = xrot + (size_t)bi * kDIM + mi * 16;
  double xs[16];
#pragma unroll
  for (int d = 0; d < 16; ++d) xs[d] = xv[d];
  const float* cm = cb + (size_t)mi * (kK * 16);
  double best = 1e300; int bidx = 0;
#pragma unroll
  for (int j = 0; j < 4; ++j) {
    const int k = lane * 4 + j;
    const float* ck = cm + k * 16;
    double s = 0.0;
#pragma unroll
    for (int d = 0; d < 16; ++d) {
      const double t = (double)ck[d] - xs[d];
      s = fma(t, t, s);
    }
    if (s < best) { best = s; bidx = k; }
  }
#pragma unroll
  for (int off = 32; off; off >>= 1) {
    const double ob = __shfl_xor(best, off);
    const int    oi = __shfl_xor(bidx, off);
    if (ob < best || (ob == best && oi < bidx)) { best = ob; bidx = oi; }
  }
  if (lane == 0) minidx[wid] = bidx;
}

__global__ __launch_bounds__(256)
void finalize_k(float* a, const float* __restrict__ gumbel,
                const int* __restrict__ minidx, const float* __restrict__ interp_param)
{
  const int wid  = (int)blockIdx.x * 4 + ((int)threadIdx.x >> 6);
  const int lane = (int)threadIdx.x & 63;
  const double interp = 1.0 / (1.0 + exp(-(double)interp_param[0]));
  const double w = 1.0 - interp;
  const double bonus = interp * 10.0;
  const int mi = minidx[wid];
  const size_t base = (size_t)wid * 256 + lane * 4;
  const float4 av = *(const float4*)&a[base];
  const float4 gv = *(const float4*)&gumbel[base];
  const int k0 = lane * 4;
  double lg[4] = {w * (double)av.x + (double)gv.x,
                  w * (double)av.y + (double)gv.y,
                  w * (double)av.z + (double)gv.z,
                  w * (double)av.w + (double)gv.w};
#pragma unroll
  for (int j = 0; j < 4; ++j)
    if (k0 + j == mi) lg[j] += bonus;

  double best = -1e300; int bk = 0;
#pragma unroll
  for (int j = 0; j < 4; ++j)
    if (lg[j] > best) { best = lg[j]; bk = k0 + j; }
#pragma unroll
  for (int off = 32; off; off >>= 1) {
    const double ob = __shfl_xor(best, off);
    const int    oi = __shfl_xor(bk, off);
    if (ob > best || (ob == best && oi < bk)) { best = ob; bk = oi; }
  }
  float4 o;
  o.x = (k0 + 0 == bk) ? 1.f : 0.f;
  o.y = (k0 + 1 == bk) ? 1.f : 0.f;
  o.z = (k0 + 2 == bk) ? 1.f : 0.f;
  o.w = (k0 + 3 == bk) ? 1.f : 0.f;
  *(float4*)&a[base] = o;
}

// ===========================================================================
extern "C" void kernel_launch(void* const* d_in, const int* in_sizes, int n_in,
                              void* d_out, int out_size, void* d_ws, size_t ws_size,
                              hipStream_t stream)
{
  const float* x      = (const float*)d_in[0];
  const float* cb     = (const float*)d_in[1];
  const float* rot1   = (const float*)d_in[2];
  const float* ln_g   = (const float*)d_in[3];
  const float* ln_b   = (const float*)d_in[4];
  const float* l1_w   = (const float*)d_in[5];
  const float* l1_b   = (const float*)d_in[6];
  const float* mu_w   = (const float*)d_in[7];
  const float* mu_b   = (const float*)d_in[8];
  const float* sig_w  = (const float*)d_in[9];
  const float* sig_b  = (const float*)d_in[10];
  const float* rot2   = (const float*)d_in[11];
  const float* l2_w   = (const float*)d_in[12];
  const float* l2_b   = (const float*)d_in[13];
  const float* interp = (const float*)d_in[14];
  const float* noise  = (const float*)d_in[15];
  const float* gumb   = (const float*)d_in[16];

  const dim3 blk(256);
  float* aout = (float*)d_out;

  const size_t nXrot = (size_t)kB * kDIM;      // 1.57M
  const size_t nH1   = (size_t)kB * kMID;      // 18.87M
  const size_t nHH   = (size_t)kB * kH;        // 12.58M
  // fast-path layout: x_rotd f64 | xnP 3xbf16 | slog f32 | h1P 3xbf16
  // (reused as hrotP) | hP 3xbf16 | Ws3 3xbf16 (max layer) | midx
  const size_t NEED  = nXrot * 8 + nXrot * 3 * 2 + nHH * 4 + nH1 * 3 * 2
                     + nHH * 3 * 2 + (size_t)kMK * kH * 3 * 2 + (size_t)kB * kM * 4;

  if (ws_size >= NEED) {
    char* p = (char*)d_ws;
    double* x_rotd = (double*)p;              p += nXrot * 8;
    short*  xnP    = (short*)p;               p += nXrot * 3 * 2;
    float*  slog   = (float*)p;               p += nHH * 4;
    short*  h1P    = (short*)p;               p += nH1 * 3 * 2;   // later hrotP
    short*  hP     = (short*)p;               p += nHH * 3 * 2;
    short*  Ws3    = (short*)p;               p += (size_t)kMK * kH * 3 * 2;
    int*    midx   = (int*)p;
    short*  hrotP  = h1P;

    // x_rot in f64 (PQ-critical)
    gemm_nt_acc64<false, 0, double><<<dim3(kDIM / 128, kB / 128), blk, 0, stream>>>(
        x, rot1, nullptr, x_rotd, nullptr, nullptr, kDIM, kDIM);
    layernorm_sp_k<<<dim3(kB), blk, 0, stream>>>(x_rotd, ln_g, ln_b, xnP, nXrot);
    mindist_k<<<dim3(kB * kM / 4), blk, 0, stream>>>(x_rotd, cb, midx);

    // l1: h1P = split3(relu(xn @ l1_w^T + b))
    split3_k<<<dim3((unsigned)((size_t)kMID * kDIM / 2048)), blk, 0, stream>>>(
        l1_w, Ws3, (size_t)kMID * kDIM);
    gemm3_bf16<true, 2><<<dim3(kMID / 128 * (kB / 128)), blk, 0, stream>>>(
        xnP, Ws3, l1_b, h1P, nullptr, nullptr, kMID, kDIM, nH1);

    // sig: slog = h1 @ sig_w^T + b   (f32)
    split3_k<<<dim3((unsigned)((size_t)kH * kMID / 2048)), blk, 0, stream>>>(
        sig_w, Ws3, (size_t)kH * kMID);
    gemm3_bf16<true, 0><<<dim3(kH / 128 * (kB / 128)), blk, 0, stream>>>(
        h1P, Ws3, sig_b, slog, nullptr, nullptr, kH, kMID, 0);

    // mu (+fused VAE): hP = split3(tanh((h1@mu_w^T+b) + exp(slog)*noise))
    split3_k<<<dim3((unsigned)((size_t)kH * kMID / 2048)), blk, 0, stream>>>(
        mu_w, Ws3, (size_t)kH * kMID);
    gemm3_bf16<true, 3><<<dim3(kH / 128 * (kB / 128)), blk, 0, stream>>>(
        h1P, Ws3, mu_b, hP, slog, noise, kH, kMID, nHH);

    // rot2: hrotP = split3(h @ rot2^T)   (into h1P slot — h1P not read here)
    split3_k<<<dim3((unsigned)((size_t)kH * kH / 2048)), blk, 0, stream>>>(
        rot2, Ws3, (size_t)kH * kH);
    gemm3_bf16<false, 4><<<dim3(kH / 128 * (kB / 128)), blk, 0, stream>>>(
        hP, Ws3, nullptr, hrotP, nullptr, nullptr, kH, kH, nHH);

    // l2: a = relu(hrot @ l2_w^T + b)  (f32 into d_out)
    split3_k<<<dim3((unsigned)((size_t)kMK * kH / 2048)), blk, 0, stream>>>(
        l2_w, Ws3, (size_t)kMK * kH);
    gemm3_bf16<true, 1><<<dim3(kMK / 128 * (kB / 128)), blk, 0, stream>>>(
        hrotP, Ws3, l2_b, aout, nullptr, nullptr, kMK, kH, 0);

    finalize_k<<<dim3(kB * kM / 4), blk, 0, stream>>>(aout, gumb, midx, interp);
    return;
  }

  // ---- fallback: all-f64 path (proven round 2) ----
  char* wsb    = (char*)d_ws;
  double* x_rotd = (double*)wsb;
  float*  xn     = (float*)(wsb + (size_t)kB * kDIM * 8);
  float*  h1     = xn   + (size_t)kB * kDIM;
  float*  slog   = h1   + (size_t)kB * kMID;
  int*    midx   = (int*)(slog + (size_t)kB * kH);
  float*  hrot   = h1;

  gemm_nt_acc64<false, 0, double><<<dim3(kDIM / 128, kB / 128), blk, 0, stream>>>(
      x, rot1, nullptr, x_rotd, nullptr, nullptr, kDIM, kDIM);
  layernorm_f32_k<<<dim3(kB), blk, 0, stream>>>(x_rotd, ln_g, ln_b, xn);
  mindist_k<<<dim3(kB * kM / 4), blk, 0, stream>>>(x_rotd, cb, midx);
  gemm_nt_acc64<true, 1, float><<<dim3(kMID / 128, kB / 128), blk, 0, stream>>>(
      xn, l1_w, l1_b, h1, nullptr, nullptr, kMID, kDIM);
  gemm_nt_acc64<true, 0, float><<<dim3(kH / 128, kB / 128), blk, 0, stream>>>(
      h1, sig_w, sig_b, slog, nullptr, nullptr, kH, kMID);
  gemm_nt_acc64<true, 2, float><<<dim3(kH / 128, kB / 128), blk, 0, stream>>>(
      h1, mu_w, mu_b, slog, slog, noise, kH, kMID);
  gemm_nt_acc64<false, 0, float><<<dim3(kH / 128, kB / 128), blk, 0, stream>>>(
      slog, rot2, nullptr, hrot, nullptr, nullptr, kH, kH);
  gemm_nt_acc64<true, 1, float><<<dim3(kMK / 128, kB / 128), blk, 0, stream>>>(
      hrot, l2_w, l2_b, aout, nullptr, nullptr, kMK, kH);
  finalize_k<<<dim3(kB * kM / 4), blk, 0, stream>>>(aout, gumb, midx, interp);
}

// Round 12
// 5999.185 us; speedup vs baseline: 1.0535x; 1.0535x over previous
//
#include <hip/hip_runtime.h>
#include <cstddef>
#include <cstdint>

constexpr int kDIM = 768;
constexpr int kM   = 48;
constexpr int kK   = 256;
constexpr int kB   = 2048;
constexpr int kMID = 9216;
constexpr int kH   = 6144;
constexpr int kMK  = 12288;

using bf8v  = __attribute__((ext_vector_type(8))) short;
using f32x4 = __attribute__((ext_vector_type(4))) float;
using s8v   = __attribute__((ext_vector_type(8))) short;

#define GLL16(SRC, DST) __builtin_amdgcn_global_load_lds( \
    (const __attribute__((address_space(1))) void*)(SRC), \
    (__attribute__((address_space(3))) void*)(DST), 16, 0, 0)

// ===========================================================================
// f64-accumulating vector GEMM (proven). rot1 fast path + full fallback path.
// ===========================================================================
template<bool HASBIAS, int EPI, typename OUT_T>
__global__ __launch_bounds__(256)
void gemm_nt_acc64(const float* __restrict__ A, const float* __restrict__ W,
                   const float* __restrict__ bias, OUT_T* C,
                   const float* zslog, const float* __restrict__ znoise,
                   int N, int Kd)
{
  __shared__ float As[16][132];
  __shared__ float Bs[16][132];
  const int tid  = (int)threadIdx.x;
  const int row0 = (int)blockIdx.y * 128;
  const int col0 = (int)blockIdx.x * 128;
  const int ty = tid >> 4, tx = tid & 15;
  const int i0 = ty * 8, j0 = tx * 8;
  const int fi1 = tid >> 2;
  const int fi2 = fi1 + 64;
  const int kc  = (tid & 3) * 4;

  const float* Ap1 = A + (size_t)(row0 + fi1) * Kd + kc;
  const float* Ap2 = A + (size_t)(row0 + fi2) * Kd + kc;
  const float* Wp1 = W + (size_t)(col0 + fi1) * Kd + kc;
  const float* Wp2 = W + (size_t)(col0 + fi2) * Kd + kc;

  double acc[8][8];
#pragma unroll
  for (int r = 0; r < 8; ++r)
#pragma unroll
    for (int c = 0; c < 8; ++c) acc[r][c] = 0.0;

  for (int kt = 0; kt < Kd; kt += 16) {
    const float4 a1 = *(const float4*)(Ap1 + kt);
    const float4 a2 = *(const float4*)(Ap2 + kt);
    const float4 b1 = *(const float4*)(Wp1 + kt);
    const float4 b2 = *(const float4*)(Wp2 + kt);
    As[kc + 0][fi1] = a1.x; As[kc + 1][fi1] = a1.y; As[kc + 2][fi1] = a1.z; As[kc + 3][fi1] = a1.w;
    As[kc + 0][fi2] = a2.x; As[kc + 1][fi2] = a2.y; As[kc + 2][fi2] = a2.z; As[kc + 3][fi2] = a2.w;
    Bs[kc + 0][fi1] = b1.x; Bs[kc + 1][fi1] = b1.y; Bs[kc + 2][fi1] = b1.z; Bs[kc + 3][fi1] = b1.w;
    Bs[kc + 0][fi2] = b2.x; Bs[kc + 1][fi2] = b2.y; Bs[kc + 2][fi2] = b2.z; Bs[kc + 3][fi2] = b2.w;
    __syncthreads();
#pragma unroll
    for (int kk = 0; kk < 16; ++kk) {
      const float4 av0 = *(const float4*)&As[kk][i0];
      const float4 av1 = *(const float4*)&As[kk][i0 + 4];
      const float4 bv0 = *(const float4*)&Bs[kk][j0];
      const float4 bv1 = *(const float4*)&Bs[kk][j0 + 4];
      const float ar[8] = {av0.x, av0.y, av0.z, av0.w, av1.x, av1.y, av1.z, av1.w};
      const float br[8] = {bv0.x, bv0.y, bv0.z, bv0.w, bv1.x, bv1.y, bv1.z, bv1.w};
      double bd[8];
#pragma unroll
      for (int c = 0; c < 8; ++c) bd[c] = (double)br[c];
#pragma unroll
      for (int r = 0; r < 8; ++r) {
        const double ad = (double)ar[r];
#pragma unroll
        for (int c = 0; c < 8; ++c)
          acc[r][c] = fma(ad, bd[c], acc[r][c]);
      }
    }
    __syncthreads();
  }

  double bvv[8];
#pragma unroll
  for (int c = 0; c < 8; ++c) bvv[c] = 0.0;
  if (HASBIAS) {
#pragma unroll
    for (int c = 0; c < 8; ++c) bvv[c] = (double)bias[col0 + j0 + c];
  }

#pragma unroll
  for (int r = 0; r < 8; ++r) {
    const size_t gbase = (size_t)(row0 + i0 + r) * N + col0 + j0;
    double o[8];
#pragma unroll
    for (int c = 0; c < 8; ++c) {
      double v = acc[r][c];
      if (HASBIAS) v += bvv[c];
      if (EPI == 1) v = fmax(v, 0.0);
      if (EPI == 2) {
        const double sg = exp((double)zslog[gbase + c]);
        v = tanh(v + sg * (double)znoise[gbase + c]);
      }
      o[c] = v;
    }
    if constexpr (sizeof(OUT_T) == 4) {
      float* dst = (float*)C + gbase;
      ((float4*)dst)[0] = make_float4((float)o[0], (float)o[1], (float)o[2], (float)o[3]);
      ((float4*)dst)[1] = make_float4((float)o[4], (float)o[5], (float)o[6], (float)o[7]);
    } else {
      double* dst = (double*)C + gbase;
#pragma unroll
      for (int c = 0; c < 8; ++c) dst[c] = o[c];
    }
  }
}

// ===========================================================================
// bf16x3 split: x = x1 + x2 + x3 exactly (f32 -> 3 bf16 planes).
// ===========================================================================
__device__ __forceinline__ unsigned short bf16rn(float f) {
  const unsigned u = __float_as_uint(f);
  return (unsigned short)((u + 0x7FFFu + ((u >> 16) & 1u)) >> 16);
}

__global__ __launch_bounds__(256)
void split3_k(const float* __restrict__ in, short* __restrict__ out, size_t n)
{
  const size_t i = ((size_t)blockIdx.x * 256 + threadIdx.x) * 8;
  const float4 v0 = *(const float4*)(in + i);
  const float4 v1 = *(const float4*)(in + i + 4);
  const float f[8] = {v0.x, v0.y, v0.z, v0.w, v1.x, v1.y, v1.z, v1.w};
  s8v o1, o2, o3;
#pragma unroll
  for (int j = 0; j < 8; ++j) {
    const unsigned short b1 = bf16rn(f[j]);
    const float r1 = f[j] - __uint_as_float((unsigned)b1 << 16);
    const unsigned short b2 = bf16rn(r1);
    const float r2 = r1 - __uint_as_float((unsigned)b2 << 16);
    const unsigned short b3 = bf16rn(r2);
    o1[j] = (short)b1; o2[j] = (short)b2; o3[j] = (short)b3;
  }
  *(s8v*)(out + i)         = o1;
  *(s8v*)(out + n + i)     = o2;
  *(s8v*)(out + 2 * n + i) = o3;
}

// ===========================================================================
// bf16x3 MFMA GEMM — round-10 PROVEN kernel (6.00ms, absmax 0.0):
// 48KB LDS single-buffer, conflict-free swizzle slot^=(row>>1)&3 (verified
// SQ_LDS_BANK_CONFLICT==0), by-minor + XCD-chunked grid order, and
// __launch_bounds__(256,3) for 3 blocks/CU inter-block drain cover (m114).
// Reverted from round-11's fused-epilogue experiment (write amplification
// 815MB vs 115MB + serial f64 tail dropped MfmaUtil 55->42).
// ===========================================================================
template<bool HASBIAS, bool RELU>
__global__ __launch_bounds__(256, 3)
void gemm3_bf16(const short* __restrict__ A3, const short* __restrict__ W3,
                const float* __restrict__ bias, float* __restrict__ C,
                int N, int Kd, int nbx)
{
  __shared__ short lds[6][4096];   // 48 KiB: tiles 0..2 = A planes, 3..5 = W planes
  short* smem = &lds[0][0];
  const char* smemc = (const char*)smem;

  // XCD-chunked bijective remap (nwg % 8 == 0 for all layers here), then
  // by-minor decomposition: consecutive wgid -> same bx (shared W panel).
  int wg = (int)blockIdx.x;
  const int nwg = (int)gridDim.x;
  if ((nwg & 7) == 0) { const int q = nwg >> 3; wg = (wg & 7) * q + (wg >> 3); }
  const int nby = kB / 128;                  // 16
  const int by = wg % nby, bx = wg / nby;
  const int row0 = by * 128, col0 = bx * 128;

  const int tid = (int)threadIdx.x;
  const int l = tid & 63, w = tid >> 6;
  const int wr = (w & 1) * 64, wc = (w >> 1) * 64;

  const size_t planeAB = (size_t)2048 * Kd * 2;   // bytes per A plane
  const size_t planeWB = (size_t)N * Kd * 2;      // bytes per W plane
  const char* A3b = (const char*)A3;
  const char* W3b = (const char*)W3;

  // --- staging addressing. Wave w stages rows su*16..su*16+31 of all 6 tiles.
  // Global source 16B-slot pre-swizzled by (row>>1)&3; for r = su*16+(l>>2)
  // and r+16 this reduces to (l>>3)&3 (identical for both row groups).
  const int su = 2 * w;
  const int r0 = su * 16 + (l >> 2), r1 = r0 + 16;
  const int qsw = (((l & 3) ^ ((l >> 3) & 3)) << 4);
  const size_t offA0 = (size_t)(row0 + r0) * Kd * 2 + qsw;
  const size_t offA1 = (size_t)(row0 + r1) * Kd * 2 + qsw;
  const size_t offW0 = (size_t)(col0 + r0) * Kd * 2 + qsw;
  const size_t offW1 = (size_t)(col0 + r1) * Kd * 2 + qsw;
  // LDS dests (uniform per wave): tile t, sub s -> t*8192 + s*1024 bytes
  short* dA0 = smem + (su + 0) * 512;
  short* dA1 = smem + (su + 1) * 512;

  // --- fragment read byte-offsets (per-lane, loop-invariant)
  int aoff[3][4], boff[3][4];
#pragma unroll
  for (int p = 0; p < 3; ++p) {
#pragma unroll
    for (int t = 0; t < 4; ++t) {
      const int Ra = wr + t * 16 + (l & 15);
      aoff[p][t] = p * 8192 + Ra * 64 + ((((l >> 4)) ^ ((Ra >> 1) & 3)) << 4);
      const int Rb = wc + t * 16 + (l & 15);
      boff[p][t] = (3 + p) * 8192 + Rb * 64 + ((((l >> 4)) ^ ((Rb >> 1) & 3)) << 4);
    }
  }

  f32x4 acc[4][4];
#pragma unroll
  for (int i = 0; i < 4; ++i)
#pragma unroll
    for (int j = 0; j < 4; ++j) acc[i][j] = f32x4{0.f, 0.f, 0.f, 0.f};

  for (int kt = 0; kt < Kd; kt += 32) {
    const size_t kb = (size_t)kt * 2;
    // issue 12 global_load_lds (6 tiles x 2 row-groups) per wave
#pragma unroll
    for (int t = 0; t < 3; ++t) {
      GLL16(A3b + t * planeAB + offA0 + kb, dA0 + t * 4096);
      GLL16(A3b + t * planeAB + offA1 + kb, dA1 + t * 4096);
    }
#pragma unroll
    for (int t = 0; t < 3; ++t) {
      GLL16(W3b + t * planeWB + offW0 + kb, dA0 + (3 + t) * 4096);
      GLL16(W3b + t * planeWB + offW1 + kb, dA1 + (3 + t) * 4096);
    }
    __syncthreads();   // drains vmcnt+lgkmcnt before barrier

    bf8v af[3][4], bf_[3][4];
#pragma unroll
    for (int p = 0; p < 3; ++p)
#pragma unroll
      for (int t = 0; t < 4; ++t) {
        af[p][t]  = *(const bf8v*)(smemc + aoff[p][t]);
        bf_[p][t] = *(const bf8v*)(smemc + boff[p][t]);
      }
#pragma unroll
    for (int tr = 0; tr < 4; ++tr)
#pragma unroll
      for (int tc = 0; tc < 4; ++tc) {
        f32x4 c = acc[tr][tc];
        c = __builtin_amdgcn_mfma_f32_16x16x32_bf16(af[0][tr], bf_[0][tc], c, 0, 0, 0);
        c = __builtin_amdgcn_mfma_f32_16x16x32_bf16(af[0][tr], bf_[1][tc], c, 0, 0, 0);
        c = __builtin_amdgcn_mfma_f32_16x16x32_bf16(af[1][tr], bf_[0][tc], c, 0, 0, 0);
        c = __builtin_amdgcn_mfma_f32_16x16x32_bf16(af[0][tr], bf_[2][tc], c, 0, 0, 0);
        c = __builtin_amdgcn_mfma_f32_16x16x32_bf16(af[2][tr], bf_[0][tc], c, 0, 0, 0);
        c = __builtin_amdgcn_mfma_f32_16x16x32_bf16(af[1][tr], bf_[1][tc], c, 0, 0, 0);
        acc[tr][tc] = c;
      }
    __syncthreads();
  }

  // epilogue: C/D layout col=lane&15, row=(lane>>4)*4+reg (HW-verified)
#pragma unroll
  for (int tc = 0; tc < 4; ++tc) {
    const int colg = col0 + wc + tc * 16 + (l & 15);
    float bv = 0.f;
    if (HASBIAS) bv = bias[colg];
#pragma unroll
    for (int tr = 0; tr < 4; ++tr) {
      const int rowg0 = row0 + wr + tr * 16 + ((l >> 4) << 2);
#pragma unroll
      for (int g = 0; g < 4; ++g) {
        float v = acc[tr][tc][g];
        if (HASBIAS) v += bv;
        if (RELU)    v = fmaxf(v, 0.f);
        C[(size_t)(rowg0 + g) * N + colg] = v;
      }
    }
  }
}

// ===========================================================================
// Small kernels (f64-critical paths)
// ===========================================================================
__global__ __launch_bounds__(256)
void layernorm_k(const double* __restrict__ in, const float* __restrict__ g,
                 const float* __restrict__ b, float* __restrict__ out)
{
  const int row = (int)blockIdx.x;
  const int tid = (int)threadIdx.x;
  const double* x = in + (size_t)row * kDIM;
  const double v0 = x[tid], v1 = x[tid + 256], v2 = x[tid + 512];
  __shared__ double red[8];
  double s = v0 + v1 + v2;
#pragma unroll
  for (int off = 32; off; off >>= 1) s += __shfl_xor(s, off);
  if ((tid & 63) == 0) red[tid >> 6] = s;
  __syncthreads();
  const double mean = (red[0] + red[1] + red[2] + red[3]) * (1.0 / 768.0);
  const double d0 = v0 - mean, d1 = v1 - mean, d2 = v2 - mean;
  double q = d0 * d0 + d1 * d1 + d2 * d2;
#pragma unroll
  for (int off = 32; off; off >>= 1) q += __shfl_xor(q, off);
  if ((tid & 63) == 0) red[4 + (tid >> 6)] = q;
  __syncthreads();
  const double var = (red[4] + red[5] + red[6] + red[7]) * (1.0 / 768.0);
  const double rs = 1.0 / sqrt(var + 1e-5);
  float* y = out + (size_t)row * kDIM;
  y[tid]       = (float)(d0 * rs * (double)g[tid]       + (double)b[tid]);
  y[tid + 256] = (float)(d1 * rs * (double)g[tid + 256] + (double)b[tid + 256]);
  y[tid + 512] = (float)(d2 * rs * (double)g[tid + 512] + (double)b[tid + 512]);
}

__global__ __launch_bounds__(256)
void zh_k(const float* __restrict__ mu, float* slog_h, const float* __restrict__ noise)
{
  const size_t i = (size_t)blockIdx.x * 256 + threadIdx.x;
  const double z = (double)mu[i] + exp((double)slog_h[i]) * (double)noise[i];
  slog_h[i] = (float)tanh(z);
}

__global__ __launch_bounds__(256)
void mindist_k(const double* __restrict__ xrot, const float* __restrict__ cb,
               int* __restrict__ minidx)
{
  const int wid  = (int)blockIdx.x * 4 + ((int)threadIdx.x >> 6);
  const int lane = (int)threadIdx.x & 63;
  const int bi = wid / kM, mi = wid % kM;
  const double* xv = xrot + (size_t)bi * kDIM + mi * 16;
  double xs[16];
#pragma unroll
  for (int d = 0; d < 16; ++d) xs[d] = xv[d];
  const float* cm = cb + (size_t)mi * (kK * 16);
  double best = 1e300; int bidx = 0;
#pragma unroll
  for (int j = 0; j < 4; ++j) {
    const int k = lane * 4 + j;
    const float* ck = cm + k * 16;
    double s = 0.0;
#pragma unroll
    for (int d = 0; d < 16; ++d) {
      const double t = (double)ck[d] - xs[d];
      s = fma(t, t, s);
    }
    if (s < best) { best = s; bidx = k; }
  }
#pragma unroll
  for (int off = 32; off; off >>= 1) {
    const double ob = __shfl_xor(best, off);
    const int    oi = __shfl_xor(bidx, off);
    if (ob < best || (ob == best && oi < bidx)) { best = ob; bidx = oi; }
  }
  if (lane == 0) minidx[wid] = bidx;
}

__global__ __launch_bounds__(256)
void finalize_k(float* a, const float* __restrict__ gumbel,
                const int* __restrict__ minidx, const float* __restrict__ interp_param)
{
  const int wid  = (int)blockIdx.x * 4 + ((int)threadIdx.x >> 6);
  const int lane = (int)threadIdx.x & 63;
  const double interp = 1.0 / (1.0 + exp(-(double)interp_param[0]));
  const double w = 1.0 - interp;
  const double bonus = interp * 10.0;
  const int mi = minidx[wid];
  const size_t base = (size_t)wid * 256 + lane * 4;
  const float4 av = *(const float4*)&a[base];
  const float4 gv = *(const float4*)&gumbel[base];
  const int k0 = lane * 4;
  double lg[4] = {w * (double)av.x + (double)gv.x,
                  w * (double)av.y + (double)gv.y,
                  w * (double)av.z + (double)gv.z,
                  w * (double)av.w + (double)gv.w};
#pragma unroll
  for (int j = 0; j < 4; ++j)
    if (k0 + j == mi) lg[j] += bonus;

  double best = -1e300; int bk = 0;
#pragma unroll
  for (int j = 0; j < 4; ++j)
    if (lg[j] > best) { best = lg[j]; bk = k0 + j; }
#pragma unroll
  for (int off = 32; off; off >>= 1) {
    const double ob = __shfl_xor(best, off);
    const int    oi = __shfl_xor(bk, off);
    if (ob > best || (ob == best && oi < bk)) { best = ob; bk = oi; }
  }
  float4 o;
  o.x = (k0 + 0 == bk) ? 1.f : 0.f;
  o.y = (k0 + 1 == bk) ? 1.f : 0.f;
  o.z = (k0 + 2 == bk) ? 1.f : 0.f;
  o.w = (k0 + 3 == bk) ? 1.f : 0.f;
  *(float4*)&a[base] = o;
}

// ===========================================================================
extern "C" void kernel_launch(void* const* d_in, const int* in_sizes, int n_in,
                              void* d_out, int out_size, void* d_ws, size_t ws_size,
                              hipStream_t stream)
{
  const float* x      = (const float*)d_in[0];
  const float* cb     = (const float*)d_in[1];
  const float* rot1   = (const float*)d_in[2];
  const float* ln_g   = (const float*)d_in[3];
  const float* ln_b   = (const float*)d_in[4];
  const float* l1_w   = (const float*)d_in[5];
  const float* l1_b   = (const float*)d_in[6];
  const float* mu_w   = (const float*)d_in[7];
  const float* mu_b   = (const float*)d_in[8];
  const float* sig_w  = (const float*)d_in[9];
  const float* sig_b  = (const float*)d_in[10];
  const float* rot2   = (const float*)d_in[11];
  const float* l2_w   = (const float*)d_in[12];
  const float* l2_b   = (const float*)d_in[13];
  const float* interp = (const float*)d_in[14];
  const float* noise  = (const float*)d_in[15];
  const float* gumb   = (const float*)d_in[16];

  const dim3 blk(256);
  float* aout = (float*)d_out;

  const size_t nXrot = (size_t)kB * kDIM;
  const size_t nH1   = (size_t)kB * kMID;
  const size_t nHH   = (size_t)kB * kH;
  const size_t NEED  = nXrot * 8 + nXrot * 4 + nH1 * 4 + nHH * 4 + nHH * 4
                     + nH1 * 3 * 2 + (size_t)kMK * kH * 3 * 2 + (size_t)kB * kM * 4;

  if (ws_size >= NEED) {
    char* p = (char*)d_ws;
    double* x_rotd = (double*)p;              p += nXrot * 8;
    float*  xn     = (float*)p;               p += nXrot * 4;
    float*  h1     = (float*)p;               p += nH1 * 4;     // later: hrot
    float*  mu     = (float*)p;               p += nHH * 4;
    float*  slog   = (float*)p;               p += nHH * 4;     // later: h
    short*  As3    = (short*)p;               p += nH1 * 3 * 2;
    short*  Ws3    = (short*)p;               p += (size_t)kMK * kH * 3 * 2;
    int*    midx   = (int*)p;

    // x_rot in f64 (PQ-critical)
    gemm_nt_acc64<false, 0, double><<<dim3(kDIM / 128, kB / 128), blk, 0, stream>>>(
        x, rot1, nullptr, x_rotd, nullptr, nullptr, kDIM, kDIM);
    layernorm_k<<<dim3(kB), blk, 0, stream>>>(x_rotd, ln_g, ln_b, xn);
    mindist_k<<<dim3(kB * kM / 4), blk, 0, stream>>>(x_rotd, cb, midx);

    // l1: h1 = relu(xn @ l1_w^T + b)
    split3_k<<<dim3((unsigned)(nXrot / 2048)), blk, 0, stream>>>(xn, As3, nXrot);
    split3_k<<<dim3((unsigned)((size_t)kMID * kDIM / 2048)), blk, 0, stream>>>(l1_w, Ws3, (size_t)kMID * kDIM);
    gemm3_bf16<true, true><<<dim3(kMID / 128 * (kB / 128)), blk, 0, stream>>>(
        As3, Ws3, l1_b, h1, kMID, kDIM, kMID / 128);

    // mu & sig share h1's split
    split3_k<<<dim3((unsigned)(nH1 / 2048)), blk, 0, stream>>>(h1, As3, nH1);
    split3_k<<<dim3((unsigned)((size_t)kH * kMID / 2048)), blk, 0, stream>>>(mu_w, Ws3, (size_t)kH * kMID);
    gemm3_bf16<true, false><<<dim3(kH / 128 * (kB / 128)), blk, 0, stream>>>(
        As3, Ws3, mu_b, mu, kH, kMID, kH / 128);
    split3_k<<<dim3((unsigned)((size_t)kH * kMID / 2048)), blk, 0, stream>>>(sig_w, Ws3, (size_t)kH * kMID);
    gemm3_bf16<true, false><<<dim3(kH / 128 * (kB / 128)), blk, 0, stream>>>(
        As3, Ws3, sig_b, slog, kH, kMID, kH / 128);

    // h = tanh(mu + exp(slog)*noise)  (in place over slog)
    zh_k<<<dim3((unsigned)(nHH / 256)), blk, 0, stream>>>(mu, slog, noise);

    // rot2: hrot = h @ rot2^T  (into h1 slot)
    split3_k<<<dim3((unsigned)(nHH / 2048)), blk, 0, stream>>>(slog, As3, nHH);
    split3_k<<<dim3((unsigned)((size_t)kH * kH / 2048)), blk, 0, stream>>>(rot2, Ws3, (size_t)kH * kH);
    gemm3_bf16<false, false><<<dim3(kH / 128 * (kB / 128)), blk, 0, stream>>>(
        As3, Ws3, nullptr, h1, kH, kH, kH / 128);

    // l2: a = relu(hrot @ l2_w^T + b)  (into d_out)
    split3_k<<<dim3((unsigned)(nHH / 2048)), blk, 0, stream>>>(h1, As3, nHH);
    split3_k<<<dim3((unsigned)((size_t)kMK * kH / 2048)), blk, 0, stream>>>(l2_w, Ws3, (size_t)kMK * kH);
    gemm3_bf16<true, true><<<dim3(kMK / 128 * (kB / 128)), blk, 0, stream>>>(
        As3, Ws3, l2_b, aout, kMK, kH, kMK / 128);

    finalize_k<<<dim3(kB * kM / 4), blk, 0, stream>>>(aout, gumb, midx, interp);
    return;
  }

  // ---- fallback: all-f64 path ----
  char* wsb    = (char*)d_ws;
  double* x_rotd = (double*)wsb;
  float*  xn     = (float*)(wsb + (size_t)kB * kDIM * 8);
  float*  h1     = xn   + (size_t)kB * kDIM;
  float*  slog   = h1   + (size_t)kB * kMID;
  int*    midx   = (int*)(slog + (size_t)kB * kH);
  float*  hrot   = h1;

  gemm_nt_acc64<false, 0, double><<<dim3(kDIM / 128, kB / 128), blk, 0, stream>>>(
      x, rot1, nullptr, x_rotd, nullptr, nullptr, kDIM, kDIM);
  layernorm_k<<<dim3(kB), blk, 0, stream>>>(x_rotd, ln_g, ln_b, xn);
  mindist_k<<<dim3(kB * kM / 4), blk, 0, stream>>>(x_rotd, cb, midx);
  gemm_nt_acc64<true, 1, float><<<dim3(kMID / 128, kB / 128), blk, 0, stream>>>(
      xn, l1_w, l1_b, h1, nullptr, nullptr, kMID, kDIM);
  gemm_nt_acc64<true, 0, float><<<dim3(kH / 128, kB / 128), blk, 0, stream>>>(
      h1, sig_w, sig_b, slog, nullptr, nullptr, kH, kMID);
  gemm_nt_acc64<true, 2, float><<<dim3(kH / 128, kB / 128), blk, 0, stream>>>(
      h1, mu_w, mu_b, slog, slog, noise, kH, kMID);
  gemm_nt_acc64<false, 0, float><<<dim3(kH / 128, kB / 128), blk, 0, stream>>>(
      slog, rot2, nullptr, hrot, nullptr, nullptr, kH, kH);
  gemm_nt_acc64<true, 1, float><<<dim3(kMK / 128, kB / 128), blk, 0, stream>>>(
      hrot, l2_w, l2_b, aout, nullptr, nullptr, kMK, kH);
  finalize_k<<<dim3(kB * kM / 4), blk, 0, stream>>>(aout, gumb, midx, interp);
}